// Round 3
// baseline (383.315 us; speedup 1.0000x reference)
//
#include <hip/hip_runtime.h>

#define NODES 40000
#define NEDGE 640000

typedef unsigned int uint;
typedef unsigned short ushort;
typedef __attribute__((ext_vector_type(8))) short short8;
typedef __attribute__((ext_vector_type(4))) float floatx4;

// ---- bf16 helpers (RNE) ----
__device__ inline ushort f2bf(float f) {
    uint u = __float_as_uint(f);
    uint r = (u + 0x7fffu + ((u >> 16) & 1u)) >> 16;
    return (ushort)r;
}
__device__ inline float bf_lo(uint u) { return __uint_as_float(u << 16); }
__device__ inline float bf_hi(uint u) { return __uint_as_float(u & 0xffff0000u); }

// ---------------- CSR build ----------------

__global__ void hist_kernel(const int* __restrict__ dst, int* __restrict__ counts, int E) {
    int e = blockIdx.x * blockDim.x + threadIdx.x;
    if (e < E) atomicAdd(&counts[dst[e]], 1);
}

__global__ __launch_bounds__(256) void s1_reduce(const int* __restrict__ counts,
                                                int* __restrict__ bsum, int N) {
    int idx = blockIdx.x * 256 + threadIdx.x;
    int c = (idx < N) ? counts[idx] : 0;
    #pragma unroll
    for (int d = 32; d; d >>= 1) c += __shfl_down(c, d, 64);
    __shared__ int ws[4];
    if ((threadIdx.x & 63) == 0) ws[threadIdx.x >> 6] = c;
    __syncthreads();
    if (threadIdx.x == 0) bsum[blockIdx.x] = ws[0] + ws[1] + ws[2] + ws[3];
}

__global__ __launch_bounds__(256) void s2_scan(const int* __restrict__ bsum,
                                               int* __restrict__ boff,
                                               int* __restrict__ rowptr_last, int B) {
    int t = threadIdx.x;
    int lane = t & 63, w = t >> 6;
    int c = (t < B) ? bsum[t] : 0;
    int v = c;
    #pragma unroll
    for (int d = 1; d < 64; d <<= 1) {
        int u = __shfl_up(v, d, 64);
        if (lane >= d) v += u;
    }
    __shared__ int ws[4];
    if (lane == 63) ws[w] = v;
    __syncthreads();
    int off = 0;
    for (int j = 0; j < w; ++j) off += ws[j];
    if (t < B) boff[t] = off + v - c;
    if (t == B - 1) rowptr_last[0] = off + v;
}

__global__ __launch_bounds__(256) void s3_scatter(const int* __restrict__ counts,
                                                  const int* __restrict__ boff,
                                                  int* __restrict__ rowptr,
                                                  int* __restrict__ cursor,
                                                  float* __restrict__ dis, int N) {
    int idx = blockIdx.x * 256 + threadIdx.x;
    int t = threadIdx.x, lane = t & 63, w = t >> 6;
    int c = (idx < N) ? counts[idx] : 0;
    int v = c;
    #pragma unroll
    for (int d = 1; d < 64; d <<= 1) {
        int u = __shfl_up(v, d, 64);
        if (lane >= d) v += u;
    }
    __shared__ int ws[4];
    if (lane == 63) ws[w] = v;
    __syncthreads();
    int off = boff[blockIdx.x];
    for (int j = 0; j < w; ++j) off += ws[j];
    if (idx < N) {
        int excl = off + v - c;
        rowptr[idx] = excl;
        cursor[idx] = excl;
        dis[idx] = rsqrtf((float)c + 1.0f);
    }
}

// fill CSR adjacency with fused per-edge norm: edata[pos] = {src, dis[src]*dis[dst]}
__global__ void fill_kernel(const int* __restrict__ src, const int* __restrict__ dst,
                            const float* __restrict__ dis,
                            int* __restrict__ cursor, int2* __restrict__ edata, int E) {
    int e = blockIdx.x * blockDim.x + threadIdx.x;
    if (e < E) {
        int s = src[e], d = dst[e];
        int pos = atomicAdd(&cursor[d], 1);
        float nrm = dis[s] * dis[d];
        int2 v; v.x = s; v.y = __float_as_int(nrm);
        edata[pos] = v;
    }
}

// ---------------- fused weight prep ----------------
// blocks 0..63:  Bp1 = pack(W_in @ W1)   (MFMA-B layout)
// blocks 64..127: Bp2 = pack(W2)
// block 128:     cvec = b_in @ W1
__global__ __launch_bounds__(256) void prep_kernel(const float* __restrict__ W_in,
                                                   const float* __restrict__ W1,
                                                   const float* __restrict__ b_in,
                                                   const float* __restrict__ W2,
                                                   ushort* __restrict__ Bp1,
                                                   ushort* __restrict__ Bp2,
                                                   float* __restrict__ cvec) {
    int b = blockIdx.x, t = threadIdx.x;
    if (b < 64) {
        int idx = b * 256 + t;
        int k = idx >> 7, n = idx & 127;
        float s = 0.f;
        for (int j = 0; j < 128; ++j) s = fmaf(W_in[k * 128 + j], W1[j * 128 + n], s);
        Bp1[((size_t)(k >> 3) * 128 + n) * 8 + (k & 7)] = f2bf(s);
    } else if (b < 128) {
        int idx = (b - 64) * 256 + t;
        int k = idx >> 7, n = idx & 127;
        Bp2[((size_t)(k >> 3) * 128 + n) * 8 + (k & 7)] = f2bf(W2[idx]);
    } else {
        if (t < 128) {
            float s = 0.f;
            for (int k = 0; k < 128; ++k) s = fmaf(b_in[k], W1[k * 128 + t], s);
            cvec[t] = s;
        }
    }
}

// ---------------- MFMA matmul: C[M,128](bf16) = A[M,128] @ B[128,128] ----------------
template <bool ABF16>
__global__ __launch_bounds__(256) void mm_mfma(const void* __restrict__ Av,
                                               const ushort* __restrict__ Bpack,
                                               ushort* __restrict__ C) {
    int t = threadIdx.x;
    int wave = t >> 6, lane = t & 63;
    int m = lane & 15, q = lane >> 4;
    int row = blockIdx.x * 64 + wave * 16 + m;

    short8 afr[4];
    if (ABF16) {
        const ushort* A = (const ushort*)Av;
        const ushort* ap = A + (size_t)row * 128 + q * 8;
        #pragma unroll
        for (int k0 = 0; k0 < 4; ++k0) afr[k0] = *(const short8*)(ap + k0 * 32);
    } else {
        const float* A = (const float*)Av;
        const float* ap = A + (size_t)row * 128 + q * 8;
        #pragma unroll
        for (int k0 = 0; k0 < 4; ++k0) {
            float4 f0 = *(const float4*)(ap + k0 * 32);
            float4 f1 = *(const float4*)(ap + k0 * 32 + 4);
            short8 a;
            a[0] = (short)f2bf(f0.x); a[1] = (short)f2bf(f0.y);
            a[2] = (short)f2bf(f0.z); a[3] = (short)f2bf(f0.w);
            a[4] = (short)f2bf(f1.x); a[5] = (short)f2bf(f1.y);
            a[6] = (short)f2bf(f1.z); a[7] = (short)f2bf(f1.w);
            afr[k0] = a;
        }
    }

    floatx4 acc[8];
    #pragma unroll
    for (int nt = 0; nt < 8; ++nt) {
        floatx4 z = {0.f, 0.f, 0.f, 0.f};
        acc[nt] = z;
    }

    #pragma unroll
    for (int nt = 0; nt < 8; ++nt) {
        #pragma unroll
        for (int k0 = 0; k0 < 4; ++k0) {
            short8 b = *(const short8*)(Bpack + ((size_t)(k0 * 4 + q) * 128 + nt * 16 + m) * 8);
            acc[nt] = __builtin_amdgcn_mfma_f32_16x16x32_bf16(afr[k0], b, acc[nt], 0, 0, 0);
        }
    }

    int orow_base = blockIdx.x * 64 + wave * 16 + q * 4;
    #pragma unroll
    for (int nt = 0; nt < 8; ++nt) {
        #pragma unroll
        for (int r = 0; r < 4; ++r) {
            C[(size_t)(orow_base + r) * 128 + nt * 16 + m] = f2bf(acc[nt][r]);
        }
    }
}

// ---------------- GCN aggregation: one wave per dst node ----------------
// Lane l preloads edge l of this row; inner loop is shfl-broadcast + independent gathers.
__global__ __launch_bounds__(256) void agg_kernel(const ushort* __restrict__ hw,
                                                  const float* __restrict__ dis,
                                                  const int* __restrict__ rowptr,
                                                  const int2* __restrict__ edata,
                                                  const float* __restrict__ cvec,
                                                  const float* __restrict__ bias,
                                                  ushort* __restrict__ out, int N) {
    int wave = (int)((blockIdx.x * 256u + threadIdx.x) >> 6);
    int lane = threadIdx.x & 63;
    if (wave >= N) return;
    int i = wave;
    int beg = rowptr[i], end = rowptr[i + 1];
    int deg = end - beg;
    const uint* __restrict__ hv = (const uint*)hw;

    float di = dis[i];
    float sii = di * di;
    uint su = hv[(size_t)i * 64 + lane];
    float a0 = sii * bf_lo(su);
    float a1 = sii * bf_hi(su);
    float sumnorm = sii;

    int col_l = 0;
    float nrm_l = 0.f;
    if (lane < deg) {
        int2 ed = edata[beg + lane];
        col_l = ed.x;
        nrm_l = __int_as_float(ed.y);
    }
    int dmain = deg > 64 ? 64 : deg;

    int j = 0;
    for (; j + 7 < dmain; j += 8) {
        int s0 = __shfl(col_l, j),     s1 = __shfl(col_l, j + 1);
        int s2 = __shfl(col_l, j + 2), s3 = __shfl(col_l, j + 3);
        int s4 = __shfl(col_l, j + 4), s5 = __shfl(col_l, j + 5);
        int s6 = __shfl(col_l, j + 6), s7 = __shfl(col_l, j + 7);
        uint u0 = hv[(size_t)s0 * 64 + lane];
        uint u1 = hv[(size_t)s1 * 64 + lane];
        uint u2 = hv[(size_t)s2 * 64 + lane];
        uint u3 = hv[(size_t)s3 * 64 + lane];
        uint u4 = hv[(size_t)s4 * 64 + lane];
        uint u5 = hv[(size_t)s5 * 64 + lane];
        uint u6 = hv[(size_t)s6 * 64 + lane];
        uint u7 = hv[(size_t)s7 * 64 + lane];
        float n0 = __shfl(nrm_l, j),     n1 = __shfl(nrm_l, j + 1);
        float n2 = __shfl(nrm_l, j + 2), n3 = __shfl(nrm_l, j + 3);
        float n4 = __shfl(nrm_l, j + 4), n5 = __shfl(nrm_l, j + 5);
        float n6 = __shfl(nrm_l, j + 6), n7 = __shfl(nrm_l, j + 7);
        a0 = fmaf(n0, bf_lo(u0), a0); a1 = fmaf(n0, bf_hi(u0), a1);
        a0 = fmaf(n1, bf_lo(u1), a0); a1 = fmaf(n1, bf_hi(u1), a1);
        a0 = fmaf(n2, bf_lo(u2), a0); a1 = fmaf(n2, bf_hi(u2), a1);
        a0 = fmaf(n3, bf_lo(u3), a0); a1 = fmaf(n3, bf_hi(u3), a1);
        a0 = fmaf(n4, bf_lo(u4), a0); a1 = fmaf(n4, bf_hi(u4), a1);
        a0 = fmaf(n5, bf_lo(u5), a0); a1 = fmaf(n5, bf_hi(u5), a1);
        a0 = fmaf(n6, bf_lo(u6), a0); a1 = fmaf(n6, bf_hi(u6), a1);
        a0 = fmaf(n7, bf_lo(u7), a0); a1 = fmaf(n7, bf_hi(u7), a1);
        sumnorm += ((n0 + n1) + (n2 + n3)) + ((n4 + n5) + (n6 + n7));
    }
    for (; j < dmain; ++j) {
        int s0 = __shfl(col_l, j);
        float n0 = __shfl(nrm_l, j);
        uint u0 = hv[(size_t)s0 * 64 + lane];
        a0 = fmaf(n0, bf_lo(u0), a0);
        a1 = fmaf(n0, bf_hi(u0), a1);
        sumnorm += n0;
    }
    // rare tail: deg > 64
    for (int e = beg + 64; e < end; ++e) {
        int2 ed = edata[e];
        float n0 = __int_as_float(ed.y);
        uint u0 = hv[(size_t)ed.x * 64 + lane];
        a0 = fmaf(n0, bf_lo(u0), a0);
        a1 = fmaf(n0, bf_hi(u0), a1);
        sumnorm += n0;
    }

    float c0 = 0.f, c1 = 0.f;
    if (cvec) { c0 = cvec[2 * lane]; c1 = cvec[2 * lane + 1]; }
    float b0 = bias[2 * lane], b1 = bias[2 * lane + 1];
    float o0 = fmaxf(fmaf(sumnorm, c0, a0) + b0, 0.f);
    float o1 = fmaxf(fmaf(sumnorm, c1, a1) + b1, 0.f);
    uint o = (uint)f2bf(o0) | ((uint)f2bf(o1) << 16);
    ((uint*)out)[(size_t)i * 64 + lane] = o;
}

// ---------------- pooling: uint (2 cols) per thread, fp32 accumulate ----------------
__global__ __launch_bounds__(256) void pool_kernel(const ushort* __restrict__ h,
                                                   const int* __restrict__ batch,
                                                   float* __restrict__ pool, int N) {
    int t = threadIdx.x;
    int c2 = t & 63;          // uint column index (2 bf16 features)
    int q = t >> 6;           // 0..3
    int n0 = blockIdx.x * 512 + q * 128;
    const uint* __restrict__ hv = (const uint*)h;
    int cur = -1;
    float a0 = 0.f, a1 = 0.f;
    for (int j = 0; j < 128; ++j) {
        int n = n0 + j;
        if (n >= N) break;
        int g = batch[n];
        uint u = hv[(size_t)n * 64 + c2];
        if (g != cur) {
            if (cur >= 0) {
                atomicAdd(&pool[cur * 128 + 2 * c2], a0);
                atomicAdd(&pool[cur * 128 + 2 * c2 + 1], a1);
            }
            cur = g; a0 = 0.f; a1 = 0.f;
        }
        a0 += bf_lo(u);
        a1 += bf_hi(u);
    }
    if (cur >= 0) {
        atomicAdd(&pool[cur * 128 + 2 * c2], a0);
        atomicAdd(&pool[cur * 128 + 2 * c2 + 1], a1);
    }
}

// ---------------- final MLP head ----------------
__device__ int lower_bound_dev(const int* __restrict__ a, int n, int x) {
    int lo = 0, hi = n;
    while (lo < hi) {
        int m = (lo + hi) >> 1;
        if (a[m] < x) lo = m + 1; else hi = m;
    }
    return lo;
}

__global__ __launch_bounds__(256) void final_kernel(const float* __restrict__ pool_sum,
                                                    const int* __restrict__ batch,
                                                    const float* __restrict__ Wf1,
                                                    const float* __restrict__ bf1,
                                                    const float* __restrict__ Wf2,
                                                    const float* __restrict__ bf2,
                                                    float* __restrict__ out, int N) {
    __shared__ float pooled[16][128];
    __shared__ float z[16][64];
    __shared__ int cnt[16];
    int t = threadIdx.x;
    if (t < 16) {
        int lo = lower_bound_dev(batch, N, t);
        int hi = lower_bound_dev(batch, N, t + 1);
        cnt[t] = hi - lo;
    }
    __syncthreads();
    for (int idx = t; idx < 2048; idx += 256) {
        int g = idx >> 7, c = idx & 127;
        float cn = (float)(cnt[g] > 1 ? cnt[g] : 1);
        pooled[g][c] = pool_sum[idx] / cn;
    }
    __syncthreads();
    for (int idx = t; idx < 1024; idx += 256) {
        int g = idx >> 6, j = idx & 63;
        float s = bf1[j];
        for (int k = 0; k < 128; ++k) s = fmaf(pooled[g][k], Wf1[k * 64 + j], s);
        z[g][j] = fmaxf(s, 0.f);
    }
    __syncthreads();
    if (t < 160) {
        int g = t / 10, k = t % 10;
        float s = bf2[k];
        for (int j = 0; j < 64; ++j) s = fmaf(z[g][j], Wf2[j * 10 + k], s);
        out[t] = s;
    }
}

// ---------------- launch ----------------

extern "C" void kernel_launch(void* const* d_in, const int* in_sizes, int n_in,
                              void* d_out, int out_size, void* d_ws, size_t ws_size,
                              hipStream_t stream) {
    const float* x    = (const float*)d_in[0];
    const int* edge   = (const int*)d_in[1];   // [2, E]
    const int* batch  = (const int*)d_in[2];
    const float* W_in = (const float*)d_in[3];
    const float* b_in = (const float*)d_in[4];
    const float* W1   = (const float*)d_in[5];
    const float* b1   = (const float*)d_in[6];
    const float* W2   = (const float*)d_in[7];
    const float* b2   = (const float*)d_in[8];
    const float* Wf1  = (const float*)d_in[9];
    const float* bf1  = (const float*)d_in[10];
    const float* Wf2  = (const float*)d_in[11];
    const float* bf2  = (const float*)d_in[12];
    float* out = (float*)d_out;

    const int N = NODES, E = NEDGE;
    const int NB = (N + 255) / 256;  // 157

    char* ws = (char*)d_ws;
    size_t off = 0;
    auto alloc = [&](size_t bytes) -> void* {
        void* p = ws + off;
        off += (bytes + 511) & ~(size_t)511;
        return p;
    };
    // counts + pools adjacent -> single memset covers both
    int* counts   = (int*)alloc((size_t)N * 4);          // padded to 160256
    float* pools  = (float*)alloc(16 * 128 * 4);         // 8192
    size_t zero_bytes = ((size_t)N * 4 + 511 & ~(size_t)511) + 16 * 128 * 4;
    ushort* bufA  = (ushort*)alloc((size_t)N * 128 * 2);
    ushort* bufB  = (ushort*)alloc((size_t)N * 128 * 2);
    ushort* Bp1   = (ushort*)alloc(128 * 128 * 2);
    ushort* Bp2   = (ushort*)alloc(128 * 128 * 2);
    float* cvec   = (float*)alloc(128 * 4);
    float* dis    = (float*)alloc((size_t)N * 4);
    int* rowptr   = (int*)alloc((size_t)(N + 1) * 4);
    int* cursor   = (int*)alloc((size_t)N * 4);
    int* bsum     = (int*)alloc((size_t)NB * 4);
    int* boff     = (int*)alloc((size_t)NB * 4);
    int2* edata   = (int2*)alloc((size_t)E * 8);

    hipMemsetAsync(counts, 0, zero_bytes, stream);

    // CSR build
    hist_kernel<<<(E + 255) / 256, 256, 0, stream>>>(edge + E, counts, E);
    s1_reduce<<<NB, 256, 0, stream>>>(counts, bsum, N);
    s2_scan<<<1, 256, 0, stream>>>(bsum, boff, rowptr + N, NB);
    s3_scatter<<<NB, 256, 0, stream>>>(counts, boff, rowptr, cursor, dis, N);
    fill_kernel<<<(E + 255) / 256, 256, 0, stream>>>(edge, edge + E, dis, cursor, edata, E);

    // weights prep (fused)
    prep_kernel<<<129, 256, 0, stream>>>(W_in, W1, b_in, W2, Bp1, Bp2, cvec);

    // layer 1
    mm_mfma<false><<<N / 64, 256, 0, stream>>>(x, Bp1, bufA);
    agg_kernel<<<N / 4, 256, 0, stream>>>(bufA, dis, rowptr, edata, cvec, b1, bufB, N);

    // layer 2
    mm_mfma<true><<<N / 64, 256, 0, stream>>>(bufB, Bp2, bufA);
    agg_kernel<<<N / 4, 256, 0, stream>>>(bufA, dis, rowptr, edata, nullptr, b2, bufB, N);

    // mean pool + MLP head
    pool_kernel<<<(N + 511) / 512, 256, 0, stream>>>(bufB, batch, pools, N);
    final_kernel<<<1, 256, 0, stream>>>(pools, batch, Wf1, bf1, Wf2, bf2, out, N);
}

// Round 4
// 306.544 us; speedup vs baseline: 1.2504x; 1.2504x over previous
//
#include <hip/hip_runtime.h>

#define NODES 40000
#define NEDGE 640000

typedef unsigned int uint;
typedef unsigned short ushort;
typedef __attribute__((ext_vector_type(8))) short short8;
typedef __attribute__((ext_vector_type(4))) float floatx4;

// ---- bf16 helpers (RNE) ----
__device__ inline ushort f2bf(float f) {
    uint u = __float_as_uint(f);
    uint r = (u + 0x7fffu + ((u >> 16) & 1u)) >> 16;
    return (ushort)r;
}
__device__ inline float bf_lo(uint u) { return __uint_as_float(u << 16); }
__device__ inline float bf_hi(uint u) { return __uint_as_float(u & 0xffff0000u); }

// ---------------- CSR build ----------------

__global__ void hist_kernel(const int* __restrict__ dst, int* __restrict__ counts, int E) {
    int e = blockIdx.x * blockDim.x + threadIdx.x;
    if (e < E) atomicAdd(&counts[dst[e]], 1);
}

__global__ __launch_bounds__(256) void s1_reduce(const int* __restrict__ counts,
                                                int* __restrict__ bsum, int N) {
    int idx = blockIdx.x * 256 + threadIdx.x;
    int c = (idx < N) ? counts[idx] : 0;
    #pragma unroll
    for (int d = 32; d; d >>= 1) c += __shfl_down(c, d, 64);
    __shared__ int ws[4];
    if ((threadIdx.x & 63) == 0) ws[threadIdx.x >> 6] = c;
    __syncthreads();
    if (threadIdx.x == 0) bsum[blockIdx.x] = ws[0] + ws[1] + ws[2] + ws[3];
}

__global__ __launch_bounds__(256) void s2_scan(const int* __restrict__ bsum,
                                               int* __restrict__ boff,
                                               int* __restrict__ rowptr_last, int B) {
    int t = threadIdx.x;
    int lane = t & 63, w = t >> 6;
    int c = (t < B) ? bsum[t] : 0;
    int v = c;
    #pragma unroll
    for (int d = 1; d < 64; d <<= 1) {
        int u = __shfl_up(v, d, 64);
        if (lane >= d) v += u;
    }
    __shared__ int ws[4];
    if (lane == 63) ws[w] = v;
    __syncthreads();
    int off = 0;
    for (int j = 0; j < w; ++j) off += ws[j];
    if (t < B) boff[t] = off + v - c;
    if (t == B - 1) rowptr_last[0] = off + v;
}

__global__ __launch_bounds__(256) void s3_scatter(const int* __restrict__ counts,
                                                  const int* __restrict__ boff,
                                                  int* __restrict__ rowptr,
                                                  int* __restrict__ cursor,
                                                  float* __restrict__ dis, int N) {
    int idx = blockIdx.x * 256 + threadIdx.x;
    int t = threadIdx.x, lane = t & 63, w = t >> 6;
    int c = (idx < N) ? counts[idx] : 0;
    int v = c;
    #pragma unroll
    for (int d = 1; d < 64; d <<= 1) {
        int u = __shfl_up(v, d, 64);
        if (lane >= d) v += u;
    }
    __shared__ int ws[4];
    if (lane == 63) ws[w] = v;
    __syncthreads();
    int off = boff[blockIdx.x];
    for (int j = 0; j < w; ++j) off += ws[j];
    if (idx < N) {
        int excl = off + v - c;
        rowptr[idx] = excl;
        cursor[idx] = excl;
        dis[idx] = rsqrtf((float)c + 1.0f);
    }
}

// fill CSR adjacency with fused per-edge norm: edata[pos] = {src, dis[src]*dis[dst]}
__global__ void fill_kernel(const int* __restrict__ src, const int* __restrict__ dst,
                            const float* __restrict__ dis,
                            int* __restrict__ cursor, int2* __restrict__ edata, int E) {
    int e = blockIdx.x * blockDim.x + threadIdx.x;
    if (e < E) {
        int s = src[e], d = dst[e];
        int pos = atomicAdd(&cursor[d], 1);
        float nrm = dis[s] * dis[d];
        int2 v; v.x = s; v.y = __float_as_int(nrm);
        edata[pos] = v;
    }
}

// ---------------- fused weight prep ----------------
__global__ __launch_bounds__(256) void prep_kernel(const float* __restrict__ W_in,
                                                   const float* __restrict__ W1,
                                                   const float* __restrict__ b_in,
                                                   const float* __restrict__ W2,
                                                   ushort* __restrict__ Bp1,
                                                   ushort* __restrict__ Bp2,
                                                   float* __restrict__ cvec) {
    int b = blockIdx.x, t = threadIdx.x;
    if (b < 64) {
        int idx = b * 256 + t;
        int k = idx >> 7, n = idx & 127;
        float s = 0.f;
        for (int j = 0; j < 128; ++j) s = fmaf(W_in[k * 128 + j], W1[j * 128 + n], s);
        Bp1[((size_t)(k >> 3) * 128 + n) * 8 + (k & 7)] = f2bf(s);
    } else if (b < 128) {
        int idx = (b - 64) * 256 + t;
        int k = idx >> 7, n = idx & 127;
        Bp2[((size_t)(k >> 3) * 128 + n) * 8 + (k & 7)] = f2bf(W2[idx]);
    } else {
        if (t < 128) {
            float s = 0.f;
            for (int k = 0; k < 128; ++k) s = fmaf(b_in[k], W1[k * 128 + t], s);
            cvec[t] = s;
        }
    }
}

// ---------------- MFMA matmul: C[M,128](bf16) = A[M,128] @ B[128,128] ----------------
template <bool ABF16>
__global__ __launch_bounds__(256) void mm_mfma(const void* __restrict__ Av,
                                               const ushort* __restrict__ Bpack,
                                               ushort* __restrict__ C) {
    int t = threadIdx.x;
    int wave = t >> 6, lane = t & 63;
    int m = lane & 15, q = lane >> 4;
    int row = blockIdx.x * 64 + wave * 16 + m;

    short8 afr[4];
    if (ABF16) {
        const ushort* A = (const ushort*)Av;
        const ushort* ap = A + (size_t)row * 128 + q * 8;
        #pragma unroll
        for (int k0 = 0; k0 < 4; ++k0) afr[k0] = *(const short8*)(ap + k0 * 32);
    } else {
        const float* A = (const float*)Av;
        const float* ap = A + (size_t)row * 128 + q * 8;
        #pragma unroll
        for (int k0 = 0; k0 < 4; ++k0) {
            float4 f0 = *(const float4*)(ap + k0 * 32);
            float4 f1 = *(const float4*)(ap + k0 * 32 + 4);
            short8 a;
            a[0] = (short)f2bf(f0.x); a[1] = (short)f2bf(f0.y);
            a[2] = (short)f2bf(f0.z); a[3] = (short)f2bf(f0.w);
            a[4] = (short)f2bf(f1.x); a[5] = (short)f2bf(f1.y);
            a[6] = (short)f2bf(f1.z); a[7] = (short)f2bf(f1.w);
            afr[k0] = a;
        }
    }

    floatx4 acc[8];
    #pragma unroll
    for (int nt = 0; nt < 8; ++nt) {
        floatx4 z = {0.f, 0.f, 0.f, 0.f};
        acc[nt] = z;
    }

    #pragma unroll
    for (int nt = 0; nt < 8; ++nt) {
        #pragma unroll
        for (int k0 = 0; k0 < 4; ++k0) {
            short8 b = *(const short8*)(Bpack + ((size_t)(k0 * 4 + q) * 128 + nt * 16 + m) * 8);
            acc[nt] = __builtin_amdgcn_mfma_f32_16x16x32_bf16(afr[k0], b, acc[nt], 0, 0, 0);
        }
    }

    int orow_base = blockIdx.x * 64 + wave * 16 + q * 4;
    #pragma unroll
    for (int nt = 0; nt < 8; ++nt) {
        #pragma unroll
        for (int r = 0; r < 4; ++r) {
            C[(size_t)(orow_base + r) * 128 + nt * 16 + m] = f2bf(acc[nt][r]);
        }
    }
}

// ---------------- GCN aggregation: one wave per dst node ----------------
// edata holds {src, norm} per edge -> per edge: one wave-uniform 8B load + one
// independent 256B row gather. No dependent random scalar loads, no shfl.
__global__ __launch_bounds__(256) void agg_kernel(const ushort* __restrict__ hw,
                                                  const float* __restrict__ dis,
                                                  const int* __restrict__ rowptr,
                                                  const int2* __restrict__ edata,
                                                  const float* __restrict__ cvec,
                                                  const float* __restrict__ bias,
                                                  ushort* __restrict__ out, int N) {
    int wave = (int)((blockIdx.x * 256u + threadIdx.x) >> 6);
    int lane = threadIdx.x & 63;
    if (wave >= N) return;
    int i = wave;
    int beg = rowptr[i], end = rowptr[i + 1];
    const uint* __restrict__ hv = (const uint*)hw;

    float di = dis[i];
    float sii = di * di;
    uint su = hv[(size_t)i * 64 + lane];
    float a0 = sii * bf_lo(su);
    float a1 = sii * bf_hi(su);
    float sumnorm = sii;

    int e = beg;
    for (; e + 3 < end; e += 4) {
        int2 e0 = edata[e],     e1 = edata[e + 1];
        int2 e2 = edata[e + 2], e3 = edata[e + 3];
        uint u0 = hv[(size_t)e0.x * 64 + lane];
        uint u1 = hv[(size_t)e1.x * 64 + lane];
        uint u2 = hv[(size_t)e2.x * 64 + lane];
        uint u3 = hv[(size_t)e3.x * 64 + lane];
        float n0 = __int_as_float(e0.y), n1 = __int_as_float(e1.y);
        float n2 = __int_as_float(e2.y), n3 = __int_as_float(e3.y);
        a0 = fmaf(n0, bf_lo(u0), a0); a1 = fmaf(n0, bf_hi(u0), a1);
        a0 = fmaf(n1, bf_lo(u1), a0); a1 = fmaf(n1, bf_hi(u1), a1);
        a0 = fmaf(n2, bf_lo(u2), a0); a1 = fmaf(n2, bf_hi(u2), a1);
        a0 = fmaf(n3, bf_lo(u3), a0); a1 = fmaf(n3, bf_hi(u3), a1);
        sumnorm += (n0 + n1) + (n2 + n3);
    }
    for (; e < end; ++e) {
        int2 e0 = edata[e];
        float n0 = __int_as_float(e0.y);
        uint u0 = hv[(size_t)e0.x * 64 + lane];
        a0 = fmaf(n0, bf_lo(u0), a0);
        a1 = fmaf(n0, bf_hi(u0), a1);
        sumnorm += n0;
    }

    float c0 = 0.f, c1 = 0.f;
    if (cvec) { c0 = cvec[2 * lane]; c1 = cvec[2 * lane + 1]; }
    float b0 = bias[2 * lane], b1 = bias[2 * lane + 1];
    float o0 = fmaxf(fmaf(sumnorm, c0, a0) + b0, 0.f);
    float o1 = fmaxf(fmaf(sumnorm, c1, a1) + b1, 0.f);
    uint o = (uint)f2bf(o0) | ((uint)f2bf(o1) << 16);
    ((uint*)out)[(size_t)i * 64 + lane] = o;
}

// ---------------- pooling: uint (2 cols) per thread, fp32 accumulate ----------------
__global__ __launch_bounds__(256) void pool_kernel(const ushort* __restrict__ h,
                                                   const int* __restrict__ batch,
                                                   float* __restrict__ pool, int N) {
    int t = threadIdx.x;
    int c2 = t & 63;
    int q = t >> 6;
    int n0 = blockIdx.x * 512 + q * 128;
    const uint* __restrict__ hv = (const uint*)h;
    int cur = -1;
    float a0 = 0.f, a1 = 0.f;
    for (int j = 0; j < 128; ++j) {
        int n = n0 + j;
        if (n >= N) break;
        int g = batch[n];
        uint u = hv[(size_t)n * 64 + c2];
        if (g != cur) {
            if (cur >= 0) {
                atomicAdd(&pool[cur * 128 + 2 * c2], a0);
                atomicAdd(&pool[cur * 128 + 2 * c2 + 1], a1);
            }
            cur = g; a0 = 0.f; a1 = 0.f;
        }
        a0 += bf_lo(u);
        a1 += bf_hi(u);
    }
    if (cur >= 0) {
        atomicAdd(&pool[cur * 128 + 2 * c2], a0);
        atomicAdd(&pool[cur * 128 + 2 * c2 + 1], a1);
    }
}

// ---------------- final MLP head ----------------
__device__ int lower_bound_dev(const int* __restrict__ a, int n, int x) {
    int lo = 0, hi = n;
    while (lo < hi) {
        int m = (lo + hi) >> 1;
        if (a[m] < x) lo = m + 1; else hi = m;
    }
    return lo;
}

__global__ __launch_bounds__(256) void final_kernel(const float* __restrict__ pool_sum,
                                                    const int* __restrict__ batch,
                                                    const float* __restrict__ Wf1,
                                                    const float* __restrict__ bf1,
                                                    const float* __restrict__ Wf2,
                                                    const float* __restrict__ bf2,
                                                    float* __restrict__ out, int N) {
    __shared__ float pooled[16][128];
    __shared__ float z[16][64];
    __shared__ int cnt[16];
    int t = threadIdx.x;
    if (t < 16) {
        int lo = lower_bound_dev(batch, N, t);
        int hi = lower_bound_dev(batch, N, t + 1);
        cnt[t] = hi - lo;
    }
    __syncthreads();
    for (int idx = t; idx < 2048; idx += 256) {
        int g = idx >> 7, c = idx & 127;
        float cn = (float)(cnt[g] > 1 ? cnt[g] : 1);
        pooled[g][c] = pool_sum[idx] / cn;
    }
    __syncthreads();
    for (int idx = t; idx < 1024; idx += 256) {
        int g = idx >> 6, j = idx & 63;
        float s = bf1[j];
        for (int k = 0; k < 128; ++k) s = fmaf(pooled[g][k], Wf1[k * 64 + j], s);
        z[g][j] = fmaxf(s, 0.f);
    }
    __syncthreads();
    if (t < 160) {
        int g = t / 10, k = t % 10;
        float s = bf2[k];
        for (int j = 0; j < 64; ++j) s = fmaf(z[g][j], Wf2[j * 10 + k], s);
        out[t] = s;
    }
}

// ---------------- launch ----------------

extern "C" void kernel_launch(void* const* d_in, const int* in_sizes, int n_in,
                              void* d_out, int out_size, void* d_ws, size_t ws_size,
                              hipStream_t stream) {
    const float* x    = (const float*)d_in[0];
    const int* edge   = (const int*)d_in[1];
    const int* batch  = (const int*)d_in[2];
    const float* W_in = (const float*)d_in[3];
    const float* b_in = (const float*)d_in[4];
    const float* W1   = (const float*)d_in[5];
    const float* b1   = (const float*)d_in[6];
    const float* W2   = (const float*)d_in[7];
    const float* b2   = (const float*)d_in[8];
    const float* Wf1  = (const float*)d_in[9];
    const float* bf1  = (const float*)d_in[10];
    const float* Wf2  = (const float*)d_in[11];
    const float* bf2  = (const float*)d_in[12];
    float* out = (float*)d_out;

    const int N = NODES, E = NEDGE;
    const int NB = (N + 255) / 256;

    char* ws = (char*)d_ws;
    size_t off = 0;
    auto alloc = [&](size_t bytes) -> void* {
        void* p = ws + off;
        off += (bytes + 511) & ~(size_t)511;
        return p;
    };
    int* counts   = (int*)alloc((size_t)N * 4);
    float* pools  = (float*)alloc(16 * 128 * 4);
    size_t zero_bytes = (((size_t)N * 4 + 511) & ~(size_t)511) + 16 * 128 * 4;
    ushort* bufA  = (ushort*)alloc((size_t)N * 128 * 2);
    ushort* bufB  = (ushort*)alloc((size_t)N * 128 * 2);
    ushort* Bp1   = (ushort*)alloc(128 * 128 * 2);
    ushort* Bp2   = (ushort*)alloc(128 * 128 * 2);
    float* cvec   = (float*)alloc(128 * 4);
    float* dis    = (float*)alloc((size_t)N * 4);
    int* rowptr   = (int*)alloc((size_t)(N + 1) * 4);
    int* cursor   = (int*)alloc((size_t)N * 4);
    int* bsum     = (int*)alloc((size_t)NB * 4);
    int* boff     = (int*)alloc((size_t)NB * 4);
    int2* edata   = (int2*)alloc((size_t)E * 8);

    hipMemsetAsync(counts, 0, zero_bytes, stream);

    // CSR build
    hist_kernel<<<(E + 255) / 256, 256, 0, stream>>>(edge + E, counts, E);
    s1_reduce<<<NB, 256, 0, stream>>>(counts, bsum, N);
    s2_scan<<<1, 256, 0, stream>>>(bsum, boff, rowptr + N, NB);
    s3_scatter<<<NB, 256, 0, stream>>>(counts, boff, rowptr, cursor, dis, N);
    fill_kernel<<<(E + 255) / 256, 256, 0, stream>>>(edge, edge + E, dis, cursor, edata, E);

    // weights prep (fused)
    prep_kernel<<<129, 256, 0, stream>>>(W_in, W1, b_in, W2, Bp1, Bp2, cvec);

    // layer 1
    mm_mfma<false><<<N / 64, 256, 0, stream>>>(x, Bp1, bufA);
    agg_kernel<<<N / 4, 256, 0, stream>>>(bufA, dis, rowptr, edata, cvec, b1, bufB, N);

    // layer 2
    mm_mfma<true><<<N / 64, 256, 0, stream>>>(bufB, Bp2, bufA);
    agg_kernel<<<N / 4, 256, 0, stream>>>(bufA, dis, rowptr, edata, nullptr, b2, bufB, N);

    // mean pool + MLP head
    pool_kernel<<<(N + 511) / 512, 256, 0, stream>>>(bufB, batch, pools, N);
    final_kernel<<<1, 256, 0, stream>>>(pools, batch, Wf1, bf1, Wf2, bf2, out, N);
}

// Round 5
// 280.232 us; speedup vs baseline: 1.3678x; 1.0939x over previous
//
#include <hip/hip_runtime.h>

#define NODES 40000
#define NEDGE 640000

typedef unsigned int uint;
typedef unsigned short ushort;
typedef __attribute__((ext_vector_type(8))) short short8;
typedef __attribute__((ext_vector_type(4))) float floatx4;

// ---- bf16 helpers (RNE) ----
__device__ inline ushort f2bf(float f) {
    uint u = __float_as_uint(f);
    uint r = (u + 0x7fffu + ((u >> 16) & 1u)) >> 16;
    return (ushort)r;
}
__device__ inline float bf_lo(uint u) { return __uint_as_float(u << 16); }
__device__ inline float bf_hi(uint u) { return __uint_as_float(u & 0xffff0000u); }

// ---------------- hist + weight prep (independent work, one launch) ----------------
// blocks [0,2500): histogram of dst. blocks [2500,2564): Bp1=pack(W_in@W1);
// [2564,2628): Bp2=pack(W2); block 2628: cvec=b_in@W1.
__global__ __launch_bounds__(256) void histprep_kernel(const int* __restrict__ dst,
                                                       int* __restrict__ counts,
                                                       const float* __restrict__ W_in,
                                                       const float* __restrict__ W1,
                                                       const float* __restrict__ b_in,
                                                       const float* __restrict__ W2,
                                                       ushort* __restrict__ Bp1,
                                                       ushort* __restrict__ Bp2,
                                                       float* __restrict__ cvec,
                                                       int E) {
    int b = blockIdx.x, t = threadIdx.x;
    if (b < 2500) {
        int e = b * 256 + t;
        if (e < E) atomicAdd(&counts[dst[e]], 1);
    } else if (b < 2564) {
        int idx = (b - 2500) * 256 + t;
        int k = idx >> 7, n = idx & 127;
        float s = 0.f;
        for (int j = 0; j < 128; ++j) s = fmaf(W_in[k * 128 + j], W1[j * 128 + n], s);
        Bp1[((size_t)(k >> 3) * 128 + n) * 8 + (k & 7)] = f2bf(s);
    } else if (b < 2628) {
        int idx = (b - 2564) * 256 + t;
        int k = idx >> 7, n = idx & 127;
        Bp2[((size_t)(k >> 3) * 128 + n) * 8 + (k & 7)] = f2bf(W2[idx]);
    } else {
        if (t < 128) {
            float s = 0.f;
            for (int k = 0; k < 128; ++k) s = fmaf(b_in[k], W1[k * 128 + t], s);
            cvec[t] = s;
        }
    }
}

// ---------------- scan stage 1: per-block sums ----------------
__global__ __launch_bounds__(256) void s1_reduce(const int* __restrict__ counts,
                                                 int* __restrict__ bsum, int N) {
    int idx = blockIdx.x * 256 + threadIdx.x;
    int c = (idx < N) ? counts[idx] : 0;
    #pragma unroll
    for (int d = 32; d; d >>= 1) c += __shfl_down(c, d, 64);
    __shared__ int ws[4];
    if ((threadIdx.x & 63) == 0) ws[threadIdx.x >> 6] = c;
    __syncthreads();
    if (threadIdx.x == 0) bsum[blockIdx.x] = ws[0] + ws[1] + ws[2] + ws[3];
}

// ---------------- scan stage 2 (fused): every block scans bsum itself, then
// scans its own 256 counts -> rowptr/cursor/dis ----------------
__global__ __launch_bounds__(256) void s3_kernel(const int* __restrict__ counts,
                                                 const int* __restrict__ bsum,
                                                 int* __restrict__ rowptr,
                                                 int* __restrict__ cursor,
                                                 float* __restrict__ dis, int N, int NB) {
    __shared__ int sc[256];
    __shared__ int ws[4];
    int t = threadIdx.x, lane = t & 63, w = t >> 6;
    sc[t] = (t < NB) ? bsum[t] : 0;
    __syncthreads();
    #pragma unroll
    for (int d = 1; d < 256; d <<= 1) {
        int v = (t >= d) ? sc[t - d] : 0;
        __syncthreads();
        sc[t] += v;
        __syncthreads();
    }
    int boff = (blockIdx.x == 0) ? 0 : sc[blockIdx.x - 1];
    if (blockIdx.x == 0 && t == 0) rowptr[N] = sc[NB - 1];

    int idx = blockIdx.x * 256 + t;
    int c = (idx < N) ? counts[idx] : 0;
    int v = c;
    #pragma unroll
    for (int d = 1; d < 64; d <<= 1) {
        int u = __shfl_up(v, d, 64);
        if (lane >= d) v += u;
    }
    if (lane == 63) ws[w] = v;
    __syncthreads();
    int off = boff;
    for (int j = 0; j < w; ++j) off += ws[j];
    if (idx < N) {
        int excl = off + v - c;
        rowptr[idx] = excl;
        cursor[idx] = excl;
        dis[idx] = rsqrtf((float)c + 1.0f);
    }
}

// fill CSR adjacency with fused per-edge norm: edata[pos] = {src, dis[src]*dis[dst]}
__global__ void fill_kernel(const int* __restrict__ src, const int* __restrict__ dst,
                            const float* __restrict__ dis,
                            int* __restrict__ cursor, int2* __restrict__ edata, int E) {
    int e = blockIdx.x * blockDim.x + threadIdx.x;
    if (e < E) {
        int s = src[e], d = dst[e];
        int pos = atomicAdd(&cursor[d], 1);
        float nrm = dis[s] * dis[d];
        int2 v; v.x = s; v.y = __float_as_int(nrm);
        edata[pos] = v;
    }
}

// ---------------- MFMA matmul: C[M,128](bf16) = A[M,128] @ B[128,128] ----------------
template <bool ABF16>
__global__ __launch_bounds__(256) void mm_mfma(const void* __restrict__ Av,
                                               const ushort* __restrict__ Bpack,
                                               ushort* __restrict__ C) {
    int t = threadIdx.x;
    int wave = t >> 6, lane = t & 63;
    int m = lane & 15, q = lane >> 4;
    int row = blockIdx.x * 64 + wave * 16 + m;

    short8 afr[4];
    if (ABF16) {
        const ushort* A = (const ushort*)Av;
        const ushort* ap = A + (size_t)row * 128 + q * 8;
        #pragma unroll
        for (int k0 = 0; k0 < 4; ++k0) afr[k0] = *(const short8*)(ap + k0 * 32);
    } else {
        const float* A = (const float*)Av;
        const float* ap = A + (size_t)row * 128 + q * 8;
        #pragma unroll
        for (int k0 = 0; k0 < 4; ++k0) {
            float4 f0 = *(const float4*)(ap + k0 * 32);
            float4 f1 = *(const float4*)(ap + k0 * 32 + 4);
            short8 a;
            a[0] = (short)f2bf(f0.x); a[1] = (short)f2bf(f0.y);
            a[2] = (short)f2bf(f0.z); a[3] = (short)f2bf(f0.w);
            a[4] = (short)f2bf(f1.x); a[5] = (short)f2bf(f1.y);
            a[6] = (short)f2bf(f1.z); a[7] = (short)f2bf(f1.w);
            afr[k0] = a;
        }
    }

    floatx4 acc[8];
    #pragma unroll
    for (int nt = 0; nt < 8; ++nt) {
        floatx4 z = {0.f, 0.f, 0.f, 0.f};
        acc[nt] = z;
    }

    #pragma unroll
    for (int nt = 0; nt < 8; ++nt) {
        #pragma unroll
        for (int k0 = 0; k0 < 4; ++k0) {
            short8 b = *(const short8*)(Bpack + ((size_t)(k0 * 4 + q) * 128 + nt * 16 + m) * 8);
            acc[nt] = __builtin_amdgcn_mfma_f32_16x16x32_bf16(afr[k0], b, acc[nt], 0, 0, 0);
        }
    }

    int orow_base = blockIdx.x * 64 + wave * 16 + q * 4;
    #pragma unroll
    for (int nt = 0; nt < 8; ++nt) {
        #pragma unroll
        for (int r = 0; r < 4; ++r) {
            C[(size_t)(orow_base + r) * 128 + nt * 16 + m] = f2bf(acc[nt][r]);
        }
    }
}

// ---------------- GCN aggregation: one wave per dst node ----------------
// Neighbor list preloaded to per-wave LDS (padded to x8 with {self,0} dummies);
// inner loop: LDS broadcast reads + 8 independent row gathers per iteration.
__global__ __launch_bounds__(256) void agg_kernel(const ushort* __restrict__ hw,
                                                  const float* __restrict__ dis,
                                                  const int* __restrict__ rowptr,
                                                  const int2* __restrict__ edata,
                                                  const float* __restrict__ cvec,
                                                  const float* __restrict__ bias,
                                                  ushort* __restrict__ out, int N) {
    __shared__ int2 eds[4][64];
    int wv = threadIdx.x >> 6;
    int lane = threadIdx.x & 63;
    int i = blockIdx.x * 4 + wv;
    if (i >= N) return;
    int beg = rowptr[i], end = rowptr[i + 1];
    int deg = end - beg;
    int dmain = deg > 64 ? 64 : deg;
    const uint* __restrict__ hv = (const uint*)hw;

    // preload neighbor records; pad to multiple of 8 with {self, norm=0}
    int2 ed;
    if (lane < dmain) {
        ed = edata[beg + lane];
    } else {
        ed.x = i; ed.y = 0;
    }
    eds[wv][lane] = ed;

    float di = dis[i];
    float sii = di * di;
    uint su = hv[(size_t)i * 64 + lane];
    float a0 = sii * bf_lo(su);
    float a1 = sii * bf_hi(su);
    float sumnorm = sii;

    int dpad = (dmain + 7) & ~7;
    for (int j = 0; j < dpad; j += 8) {
        int2 e0 = eds[wv][j],     e1 = eds[wv][j + 1];
        int2 e2 = eds[wv][j + 2], e3 = eds[wv][j + 3];
        int2 e4 = eds[wv][j + 4], e5 = eds[wv][j + 5];
        int2 e6 = eds[wv][j + 6], e7 = eds[wv][j + 7];
        uint u0 = hv[(size_t)e0.x * 64 + lane];
        uint u1 = hv[(size_t)e1.x * 64 + lane];
        uint u2 = hv[(size_t)e2.x * 64 + lane];
        uint u3 = hv[(size_t)e3.x * 64 + lane];
        uint u4 = hv[(size_t)e4.x * 64 + lane];
        uint u5 = hv[(size_t)e5.x * 64 + lane];
        uint u6 = hv[(size_t)e6.x * 64 + lane];
        uint u7 = hv[(size_t)e7.x * 64 + lane];
        float n0 = __int_as_float(e0.y), n1 = __int_as_float(e1.y);
        float n2 = __int_as_float(e2.y), n3 = __int_as_float(e3.y);
        float n4 = __int_as_float(e4.y), n5 = __int_as_float(e5.y);
        float n6 = __int_as_float(e6.y), n7 = __int_as_float(e7.y);
        a0 = fmaf(n0, bf_lo(u0), a0); a1 = fmaf(n0, bf_hi(u0), a1);
        a0 = fmaf(n1, bf_lo(u1), a0); a1 = fmaf(n1, bf_hi(u1), a1);
        a0 = fmaf(n2, bf_lo(u2), a0); a1 = fmaf(n2, bf_hi(u2), a1);
        a0 = fmaf(n3, bf_lo(u3), a0); a1 = fmaf(n3, bf_hi(u3), a1);
        a0 = fmaf(n4, bf_lo(u4), a0); a1 = fmaf(n4, bf_hi(u4), a1);
        a0 = fmaf(n5, bf_lo(u5), a0); a1 = fmaf(n5, bf_hi(u5), a1);
        a0 = fmaf(n6, bf_lo(u6), a0); a1 = fmaf(n6, bf_hi(u6), a1);
        a0 = fmaf(n7, bf_lo(u7), a0); a1 = fmaf(n7, bf_hi(u7), a1);
        sumnorm += ((n0 + n1) + (n2 + n3)) + ((n4 + n5) + (n6 + n7));
    }
    // rare tail: deg > 64
    for (int e = beg + 64; e < end; ++e) {
        int2 et = edata[e];
        float n0 = __int_as_float(et.y);
        uint u0 = hv[(size_t)et.x * 64 + lane];
        a0 = fmaf(n0, bf_lo(u0), a0);
        a1 = fmaf(n0, bf_hi(u0), a1);
        sumnorm += n0;
    }

    float c0 = 0.f, c1 = 0.f;
    if (cvec) { c0 = cvec[2 * lane]; c1 = cvec[2 * lane + 1]; }
    float b0 = bias[2 * lane], b1 = bias[2 * lane + 1];
    float o0 = fmaxf(fmaf(sumnorm, c0, a0) + b0, 0.f);
    float o1 = fmaxf(fmaf(sumnorm, c1, a1) + b1, 0.f);
    uint o = (uint)f2bf(o0) | ((uint)f2bf(o1) << 16);
    ((uint*)out)[(size_t)i * 64 + lane] = o;
}

// ---------------- pooling: uint (2 cols) per thread, fp32 accumulate ----------------
__global__ __launch_bounds__(256) void pool_kernel(const ushort* __restrict__ h,
                                                   const int* __restrict__ batch,
                                                   float* __restrict__ pool, int N) {
    int t = threadIdx.x;
    int c2 = t & 63;
    int q = t >> 6;
    int n0 = blockIdx.x * 512 + q * 128;
    const uint* __restrict__ hv = (const uint*)h;
    int cur = -1;
    float a0 = 0.f, a1 = 0.f;
    for (int j = 0; j < 128; ++j) {
        int n = n0 + j;
        if (n >= N) break;
        int g = batch[n];
        uint u = hv[(size_t)n * 64 + c2];
        if (g != cur) {
            if (cur >= 0) {
                atomicAdd(&pool[cur * 128 + 2 * c2], a0);
                atomicAdd(&pool[cur * 128 + 2 * c2 + 1], a1);
            }
            cur = g; a0 = 0.f; a1 = 0.f;
        }
        a0 += bf_lo(u);
        a1 += bf_hi(u);
    }
    if (cur >= 0) {
        atomicAdd(&pool[cur * 128 + 2 * c2], a0);
        atomicAdd(&pool[cur * 128 + 2 * c2 + 1], a1);
    }
}

// ---------------- final MLP head ----------------
__device__ int lower_bound_dev(const int* __restrict__ a, int n, int x) {
    int lo = 0, hi = n;
    while (lo < hi) {
        int m = (lo + hi) >> 1;
        if (a[m] < x) lo = m + 1; else hi = m;
    }
    return lo;
}

__global__ __launch_bounds__(256) void final_kernel(const float* __restrict__ pool_sum,
                                                    const int* __restrict__ batch,
                                                    const float* __restrict__ Wf1,
                                                    const float* __restrict__ bf1,
                                                    const float* __restrict__ Wf2,
                                                    const float* __restrict__ bf2,
                                                    float* __restrict__ out, int N) {
    __shared__ float pooled[16][128];
    __shared__ float z[16][64];
    __shared__ int cnt[16];
    int t = threadIdx.x;
    if (t < 16) {
        int lo = lower_bound_dev(batch, N, t);
        int hi = lower_bound_dev(batch, N, t + 1);
        cnt[t] = hi - lo;
    }
    __syncthreads();
    for (int idx = t; idx < 2048; idx += 256) {
        int g = idx >> 7, c = idx & 127;
        float cn = (float)(cnt[g] > 1 ? cnt[g] : 1);
        pooled[g][c] = pool_sum[idx] / cn;
    }
    __syncthreads();
    for (int idx = t; idx < 1024; idx += 256) {
        int g = idx >> 6, j = idx & 63;
        float s = bf1[j];
        for (int k = 0; k < 128; ++k) s = fmaf(pooled[g][k], Wf1[k * 64 + j], s);
        z[g][j] = fmaxf(s, 0.f);
    }
    __syncthreads();
    if (t < 160) {
        int g = t / 10, k = t % 10;
        float s = bf2[k];
        for (int j = 0; j < 64; ++j) s = fmaf(z[g][j], Wf2[j * 10 + k], s);
        out[t] = s;
    }
}

// ---------------- launch ----------------

extern "C" void kernel_launch(void* const* d_in, const int* in_sizes, int n_in,
                              void* d_out, int out_size, void* d_ws, size_t ws_size,
                              hipStream_t stream) {
    const float* x    = (const float*)d_in[0];
    const int* edge   = (const int*)d_in[1];
    const int* batch  = (const int*)d_in[2];
    const float* W_in = (const float*)d_in[3];
    const float* b_in = (const float*)d_in[4];
    const float* W1   = (const float*)d_in[5];
    const float* b1   = (const float*)d_in[6];
    const float* W2   = (const float*)d_in[7];
    const float* b2   = (const float*)d_in[8];
    const float* Wf1  = (const float*)d_in[9];
    const float* bf1  = (const float*)d_in[10];
    const float* Wf2  = (const float*)d_in[11];
    const float* bf2  = (const float*)d_in[12];
    float* out = (float*)d_out;

    const int N = NODES, E = NEDGE;
    const int NB = (N + 255) / 256;  // 157

    char* ws = (char*)d_ws;
    size_t off = 0;
    auto alloc = [&](size_t bytes) -> void* {
        void* p = ws + off;
        off += (bytes + 511) & ~(size_t)511;
        return p;
    };
    int* counts   = (int*)alloc((size_t)N * 4);
    float* pools  = (float*)alloc(16 * 128 * 4);
    size_t zero_bytes = (((size_t)N * 4 + 511) & ~(size_t)511) + 16 * 128 * 4;
    ushort* bufA  = (ushort*)alloc((size_t)N * 128 * 2);
    ushort* bufB  = (ushort*)alloc((size_t)N * 128 * 2);
    ushort* Bp1   = (ushort*)alloc(128 * 128 * 2);
    ushort* Bp2   = (ushort*)alloc(128 * 128 * 2);
    float* cvec   = (float*)alloc(128 * 4);
    float* dis    = (float*)alloc((size_t)N * 4);
    int* rowptr   = (int*)alloc((size_t)(N + 1) * 4);
    int* cursor   = (int*)alloc((size_t)N * 4);
    int* bsum     = (int*)alloc((size_t)NB * 4);
    int2* edata   = (int2*)alloc((size_t)E * 8);

    hipMemsetAsync(counts, 0, zero_bytes, stream);

    // CSR build + weight prep (fused into hist launch)
    histprep_kernel<<<2629, 256, 0, stream>>>(edge + E, counts, W_in, W1, b_in, W2,
                                              Bp1, Bp2, cvec, E);
    s1_reduce<<<NB, 256, 0, stream>>>(counts, bsum, N);
    s3_kernel<<<NB, 256, 0, stream>>>(counts, bsum, rowptr, cursor, dis, N, NB);
    fill_kernel<<<(E + 255) / 256, 256, 0, stream>>>(edge, edge + E, dis, cursor, edata, E);

    // layer 1
    mm_mfma<false><<<N / 64, 256, 0, stream>>>(x, Bp1, bufA);
    agg_kernel<<<N / 4, 256, 0, stream>>>(bufA, dis, rowptr, edata, cvec, b1, bufB, N);

    // layer 2
    mm_mfma<true><<<N / 64, 256, 0, stream>>>(bufB, Bp2, bufA);
    agg_kernel<<<N / 4, 256, 0, stream>>>(bufA, dis, rowptr, edata, nullptr, b2, bufB, N);

    // mean pool + MLP head
    pool_kernel<<<(N + 511) / 512, 256, 0, stream>>>(bufB, batch, pools, N);
    final_kernel<<<1, 256, 0, stream>>>(pools, batch, Wf1, bf1, Wf2, bf2, out, N);
}